// Round 1
// baseline (1851.258 us; speedup 1.0000x reference)
//
#include <hip/hip_runtime.h>

#define BB 16
#define CIN 256
#define COUT 256
#define HH 64
#define WW 64
#define SDIM 512

#define CO_TILE 16
#define TS 32
#define XT 34   // TS + 2 halo

// ---------------- kernel 1: style projection s[b,ci] ----------------
__global__ void style_proj_kernel(const float* __restrict__ style,
                                  const float* __restrict__ style_w,
                                  const float* __restrict__ style_b,
                                  float* __restrict__ s) {
    int ci = threadIdx.x;
    int b  = blockIdx.x;
    float acc = style_b[ci];
    const float* st = style + b * SDIM;
    for (int sd = 0; sd < SDIM; ++sd)
        acc += st[sd] * style_w[sd * CIN + ci];
    s[b * CIN + ci] = acc;
}

// ---------------- kernel 2a: wsq[co,ci] = sum_k w^2 ----------------
__global__ void wsq_kernel(const float* __restrict__ weight,
                           float* __restrict__ wsq) {
    int idx = blockIdx.x * blockDim.x + threadIdx.x;  // co*CIN+ci
    const float* w = weight + (size_t)idx * 9;
    float acc = 0.f;
#pragma unroll
    for (int k = 0; k < 9; ++k) acc += w[k] * w[k];
    wsq[idx] = acc;
}

// ---------------- kernel 2b: demod[b,co] ----------------
__global__ void demod_kernel(const float* __restrict__ wsq,
                             const float* __restrict__ s,
                             float* __restrict__ demod) {
    int b    = blockIdx.y;
    int co   = blockIdx.x * 4 + (threadIdx.x >> 6);
    int lane = threadIdx.x & 63;
    const float mod_scale2 = 1.0f / (float)(CIN * 9);
    float acc = 0.f;
#pragma unroll
    for (int j = 0; j < CIN / 64; ++j) {
        int ci = j * 64 + lane;
        float sv = s[b * CIN + ci];
        acc += wsq[co * CIN + ci] * sv * sv;
    }
#pragma unroll
    for (int off = 32; off > 0; off >>= 1)
        acc += __shfl_down(acc, off, 64);
    if (lane == 0)
        demod[b * COUT + co] = rsqrtf(acc * mod_scale2 + 1e-8f);
}

// ---------------- kernel 3: direct conv, shared weight, s folded into x ----
__global__ __launch_bounds__(256) void conv_kernel(
    const float* __restrict__ x, const float* __restrict__ weight,
    const float* __restrict__ s, const float* __restrict__ demod,
    float* __restrict__ out) {
    __shared__ float xs[XT * XT];
    __shared__ float ws[CO_TILE * 9];

    int b   = blockIdx.z;
    int co0 = blockIdx.x * CO_TILE;
    int ty0 = (blockIdx.y >> 1) * TS;
    int tx0 = (blockIdx.y & 1) * TS;

    int tid = threadIdx.x;
    int lx  = tid & 31;         // column within tile
    int py0 = (tid >> 5) * 4;   // 4 consecutive rows per thread

    float acc[CO_TILE][4];
#pragma unroll
    for (int c = 0; c < CO_TILE; ++c)
#pragma unroll
        for (int p = 0; p < 4; ++p) acc[c][p] = 0.f;

    for (int ci = 0; ci < CIN; ++ci) {
        float sv = s[b * CIN + ci];
        __syncthreads();  // protect LDS from previous iteration's readers
        const float* xp = x + ((size_t)(b * CIN + ci)) * (HH * WW);
        for (int idx = tid; idx < XT * XT; idx += 256) {
            int r = idx / XT, c = idx - r * XT;
            int gy = ty0 + r - 1, gx = tx0 + c - 1;
            float v = 0.f;
            if ((unsigned)gy < HH && (unsigned)gx < WW) v = xp[gy * WW + gx];
            xs[idx] = v * sv;
        }
        if (tid < CO_TILE * 9) {
            int c = tid / 9, k = tid - c * 9;
            ws[tid] = weight[(((size_t)(co0 + c)) * CIN + ci) * 9 + k];
        }
        __syncthreads();

        // 18 x-values into registers: rows py0..py0+5, cols lx..lx+2
        float xr[6][3];
#pragma unroll
        for (int r = 0; r < 6; ++r)
#pragma unroll
            for (int c = 0; c < 3; ++c)
                xr[r][c] = xs[(py0 + r) * XT + lx + c];

#pragma unroll
        for (int c = 0; c < CO_TILE; ++c) {
            float wv[9];
#pragma unroll
            for (int k = 0; k < 9; ++k) wv[k] = ws[c * 9 + k];  // broadcast, no conflict
#pragma unroll
            for (int p = 0; p < 4; ++p)
#pragma unroll
                for (int kh = 0; kh < 3; ++kh)
#pragma unroll
                    for (int kw = 0; kw < 3; ++kw)
                        acc[c][p] += xr[p + kh][kw] * wv[kh * 3 + kw];
        }
    }

    const float mod_scale = 1.0f / 48.0f;  // 1/sqrt(CIN*9)
#pragma unroll
    for (int c = 0; c < CO_TILE; ++c) {
        float dm = demod[b * COUT + co0 + c] * mod_scale;
#pragma unroll
        for (int p = 0; p < 4; ++p) {
            int gy = ty0 + py0 + p;
            int gx = tx0 + lx;
            out[(((size_t)b * COUT + co0 + c) * HH + gy) * WW + gx] = acc[c][p] * dm;
        }
    }
}

extern "C" void kernel_launch(void* const* d_in, const int* in_sizes, int n_in,
                              void* d_out, int out_size, void* d_ws, size_t ws_size,
                              hipStream_t stream) {
    const float* x       = (const float*)d_in[0];  // [16,256,64,64]
    const float* style   = (const float*)d_in[1];  // [16,512]
    const float* weight  = (const float*)d_in[2];  // [256,256,3,3]
    const float* style_w = (const float*)d_in[3];  // [512,256]
    const float* style_b = (const float*)d_in[4];  // [256]
    float* out = (float*)d_out;

    // workspace layout (floats): s[B*CIN] | wsq[COUT*CIN] | demod[B*COUT]
    float* s     = (float*)d_ws;
    float* wsq   = s + BB * CIN;
    float* demod = wsq + COUT * CIN;

    style_proj_kernel<<<BB, CIN, 0, stream>>>(style, style_w, style_b, s);
    wsq_kernel<<<(COUT * CIN) / 256, 256, 0, stream>>>(weight, wsq);
    demod_kernel<<<dim3(COUT / 4, BB), 256, 0, stream>>>(wsq, s, demod);

    dim3 grid(COUT / CO_TILE, (HH / TS) * (WW / TS), BB);
    conv_kernel<<<grid, 256, 0, stream>>>(x, weight, s, demod, out);
}

// Round 2
// 277.099 us; speedup vs baseline: 6.6809x; 6.6809x over previous
//
#include <hip/hip_runtime.h>
#include <hip/hip_bf16.h>

#define BB 16
#define CIN 256
#define COUT 256
#define HH 64
#define WW 64
#define SDIM 512
#define XP 66          // padded spatial dim
#define XPP (XP * XP)  // 4356

typedef __attribute__((ext_vector_type(8))) short bf16x8;
typedef __attribute__((ext_vector_type(4))) float f32x4;

// ---------------- kernel 1: style projection s[b,ci] ----------------
__global__ void style_proj_kernel(const float* __restrict__ style,
                                  const float* __restrict__ style_w,
                                  const float* __restrict__ style_b,
                                  float* __restrict__ s) {
    int ci = threadIdx.x;
    int b  = blockIdx.x;
    float acc = style_b[ci];
    const float* st = style + b * SDIM;
    for (int sd = 0; sd < SDIM; ++sd)
        acc += st[sd] * style_w[sd * CIN + ci];
    s[b * CIN + ci] = acc;
}

// ---------------- kernel 2a: wsq[co,ci] = sum_k w^2 (fp32, exact) ---------
__global__ void wsq_kernel(const float* __restrict__ weight,
                           float* __restrict__ wsq) {
    int idx = blockIdx.x * blockDim.x + threadIdx.x;  // co*CIN+ci
    const float* w = weight + (size_t)idx * 9;
    float acc = 0.f;
#pragma unroll
    for (int k = 0; k < 9; ++k) acc += w[k] * w[k];
    wsq[idx] = acc;
}

// ---------------- kernel 2b: demod[b,co] (fp32, exact) ----------------
__global__ void demod_kernel(const float* __restrict__ wsq,
                             const float* __restrict__ s,
                             float* __restrict__ demod) {
    int b    = blockIdx.y;
    int co   = blockIdx.x * 4 + (threadIdx.x >> 6);
    int lane = threadIdx.x & 63;
    const float mod_scale2 = 1.0f / (float)(CIN * 9);
    float acc = 0.f;
#pragma unroll
    for (int j = 0; j < CIN / 64; ++j) {
        int ci = j * 64 + lane;
        float sv = s[b * CIN + ci];
        acc += wsq[co * CIN + ci] * sv * sv;
    }
#pragma unroll
    for (int off = 32; off > 0; off >>= 1)
        acc += __shfl_down(acc, off, 64);
    if (lane == 0)
        demod[b * COUT + co] = rsqrtf(acc * mod_scale2 + 1e-8f);
}

// ---------------- kernel 3: weight transform -> bf16 wT[co][k][ci] -------
__global__ void wconv_kernel(const float* __restrict__ w,
                             __hip_bfloat16* __restrict__ wT) {
    int co = blockIdx.x;   // 256
    int ci = threadIdx.x;  // 256
#pragma unroll
    for (int k = 0; k < 9; ++k)
        wT[((size_t)co * 9 + k) * CIN + ci] =
            __float2bfloat16(w[((size_t)co * CIN + ci) * 9 + k]);
}

// -------- kernel 4: xpad[b][cc][py][px][ci32] = bf16(x * s), zero halo ----
__global__ __launch_bounds__(256) void xmod_kernel(
    const float* __restrict__ x, const float* __restrict__ s,
    __hip_bfloat16* __restrict__ xpad) {
    int py  = blockIdx.x;  // 0..65 (padded row)
    int cc  = blockIdx.y;  // 0..7  (ci chunk of 32)
    int b   = blockIdx.z;
    int tid = threadIdx.x;
    __hip_bfloat16* outp = xpad + ((size_t)(b * 8 + cc) * XPP + py * XP) * 32;
    if (py == 0 || py == XP - 1) {
        for (int f = tid; f < XP * 32; f += 256) outp[f] = __float2bfloat16(0.f);
        return;
    }
    __shared__ float lds[32 * 65];  // stride 65: conflict-free transpose
#pragma unroll
    for (int i = 0; i < 8; ++i) {
        int f = i * 256 + tid;
        int cil = f >> 6, xcol = f & 63;
        int ci = cc * 32 + cil;
        float v = x[((size_t)(b * CIN + ci) * HH + (py - 1)) * WW + xcol] *
                  s[b * CIN + ci];
        lds[cil * 65 + xcol] = v;
    }
    __syncthreads();
#pragma unroll
    for (int o = 0; o < 8; ++o) {
        int f = o * 256 + tid;
        int px = f >> 5, cil = f & 31;
        outp[(px + 1) * 32 + cil] = __float2bfloat16(lds[cil * 65 + px]);
    }
    if (tid < 32) {
        outp[tid] = __float2bfloat16(0.f);
        outp[65 * 32 + tid] = __float2bfloat16(0.f);
    }
}

// ---------------- kernel 5: implicit-GEMM conv via bf16 MFMA ----------------
// block: 4 waves = 2 co-waves x 2 row-waves -> 64 co x (2 rows x 64 px)
// wave tile: 32 co x 64 px = 2 (m) x 4 (n) tiles of 16x16x32 MFMA
__global__ __launch_bounds__(256) void conv_mfma_kernel(
    const __hip_bfloat16* __restrict__ xpad,
    const __hip_bfloat16* __restrict__ wT,
    const float* __restrict__ demod,
    float* __restrict__ out) {
    // LDS x-tile: 4 padded rows x 66 cols x 32 ci = 8448 bf16 (16.9 KB)
    __shared__ __hip_bfloat16 xs[4 * XP * 32];

    int tid  = threadIdx.x;
    int lane = tid & 63;
    int wave = tid >> 6;
    int wco  = wave >> 1;  // 0,1 : co half
    int wr   = wave & 1;   // 0,1 : output row within tile
    int n    = lane & 15;
    int quad = lane >> 4;

    int sp  = blockIdx.x;       // 0..31 spatial tile (2 rows each)
    int co0 = blockIdx.y * 64;  // 0..3
    int b   = blockIdx.z;
    int y0  = sp * 2;           // output rows y0, y0+1 ; padded rows y0..y0+3

    f32x4 acc[2][4];
#pragma unroll
    for (int i = 0; i < 2; ++i)
#pragma unroll
        for (int j = 0; j < 4; ++j) acc[i][j] = (f32x4){0.f, 0.f, 0.f, 0.f};

    for (int cc = 0; cc < 8; ++cc) {
        __syncthreads();  // prior readers done before LDS overwrite
        // stage 4 rows x 66 cols x 32 ci = 8448 bf16, fully contiguous in
        // global thanks to the [b][cc][py][px][ci32] layout: 1056 slots x 16B
        const __hip_bfloat16* src =
            xpad + ((size_t)(b * 8 + cc) * XPP + y0 * XP) * 32;
#pragma unroll
        for (int t = 0; t < 4; ++t) {
            int f = t * 256 + tid;
            __builtin_amdgcn_global_load_lds(
                (const __attribute__((address_space(1))) void*)(src + (size_t)f * 8),
                (__attribute__((address_space(3))) void*)(xs + (t * 256 + (tid & ~63)) * 8),
                16, 0, 0);
        }
        if (tid < 32) {
            int f = 1024 + tid;
            __builtin_amdgcn_global_load_lds(
                (const __attribute__((address_space(1))) void*)(src + (size_t)f * 8),
                (__attribute__((address_space(3))) void*)(xs + 1024 * 8),
                16, 0, 0);
        }
        __syncthreads();  // drains vmcnt(0) before ds_read

        // A base: wT[co][k][ci], co rows for this wave: co0 + wco*32 + i*16 + m
        const __hip_bfloat16* wbase =
            wT + ((size_t)(co0 + wco * 32) * 9) * CIN + cc * 32 + quad * 8;
#pragma unroll
        for (int k = 0; k < 9; ++k) {
            int dy = k / 3, dx = k - dy * 3;
            bf16x8 a0 = *(const bf16x8*)(wbase + ((size_t)((n)*9 + k)) * CIN);
            bf16x8 a1 = *(const bf16x8*)(wbase + ((size_t)((16 + n) * 9 + k)) * CIN);
            int ldsrow = wr + dy;
#pragma unroll
            for (int j = 0; j < 4; ++j) {
                int col = j * 16 + n + dx;
                bf16x8 bv = *(const bf16x8*)&xs[(ldsrow * XP + col) * 32 + quad * 8];
                acc[0][j] = __builtin_amdgcn_mfma_f32_16x16x32_bf16(a0, bv, acc[0][j], 0, 0, 0);
                acc[1][j] = __builtin_amdgcn_mfma_f32_16x16x32_bf16(a1, bv, acc[1][j], 0, 0, 0);
            }
        }
    }

    // epilogue: C/D layout col=lane&15 (px), row=quad*4+reg (co)
    int gy = y0 + wr;
    const float ms = 1.0f / 48.0f;  // mod_scale
#pragma unroll
    for (int i = 0; i < 2; ++i) {
        int cobase = co0 + wco * 32 + i * 16 + quad * 4;
        float d0 = demod[b * COUT + cobase + 0] * ms;
        float d1 = demod[b * COUT + cobase + 1] * ms;
        float d2 = demod[b * COUT + cobase + 2] * ms;
        float d3 = demod[b * COUT + cobase + 3] * ms;
#pragma unroll
        for (int j = 0; j < 4; ++j) {
            int gx = j * 16 + n;
            size_t o = ((size_t)(b * COUT + cobase) * HH + gy) * WW + gx;
            out[o]                 = acc[i][j][0] * d0;
            out[o + (size_t)HH*WW]     = acc[i][j][1] * d1;
            out[o + (size_t)2*HH*WW]   = acc[i][j][2] * d2;
            out[o + (size_t)3*HH*WW]   = acc[i][j][3] * d3;
        }
    }
}

extern "C" void kernel_launch(void* const* d_in, const int* in_sizes, int n_in,
                              void* d_out, int out_size, void* d_ws, size_t ws_size,
                              hipStream_t stream) {
    const float* x       = (const float*)d_in[0];  // [16,256,64,64]
    const float* style   = (const float*)d_in[1];  // [16,512]
    const float* weight  = (const float*)d_in[2];  // [256,256,3,3]
    const float* style_w = (const float*)d_in[3];  // [512,256]
    const float* style_b = (const float*)d_in[4];  // [256]
    float* out = (float*)d_out;

    // ws layout: s[4096]f | wsq[65536]f | demod[4096]f | wT[589824]bf16 |
    //            xpad[16*8*4356*32]bf16   (total ~37.2 MB)
    float* s     = (float*)d_ws;
    float* wsq   = s + BB * CIN;
    float* demod = wsq + COUT * CIN;
    __hip_bfloat16* wT   = (__hip_bfloat16*)(demod + BB * COUT);
    __hip_bfloat16* xpad = wT + (size_t)COUT * 9 * CIN;

    style_proj_kernel<<<BB, CIN, 0, stream>>>(style, style_w, style_b, s);
    wsq_kernel<<<(COUT * CIN) / 256, 256, 0, stream>>>(weight, wsq);
    demod_kernel<<<dim3(COUT / 4, BB), 256, 0, stream>>>(wsq, s, demod);
    wconv_kernel<<<COUT, CIN, 0, stream>>>(weight, wT);
    xmod_kernel<<<dim3(XP, 8, BB), 256, 0, stream>>>(x, s, xpad);

    conv_mfma_kernel<<<dim3(32, COUT / 64, BB), 256, 0, stream>>>(xpad, wT, demod, out);
}